// Round 2
// 384.735 us; speedup vs baseline: 1.0731x; 1.0731x over previous
//
#include <hip/hip_runtime.h>

// GCN layer on MI355X (gfx950) — ALL tensors fp32.
// x[100000,512], edge_index[2,3200000] i32, W1[512,16], b1[16], W2[16,2], b2[2]
//   -> out[100000,2] fp32.
//
// Folds (epilogue is linear):
//   Wc = W1@W2 [512,2],  b' = b1@W2 + b2
//   t_raw[j] = (x@Wc)[j];  after deg known: t[j] = dinv[j]*t_raw[j]
//   out_i = dinv_i * ( sum_{j->i} t_j + t_i ) + b'
//
// R7 = R6 resubmit (R6 bench died with an infra-level container failure,
// no kernel diagnostics). Only change vs R6: dropped the aggressive
// __launch_bounds__(1024, 8) occupancy request on k_bin_xw — if the
// 4-accumulator GEMV path needs >64 VGPRs that directive forces spills.
//
// R6 theory (still live): k_bin_xw counters showed 18% HBM / 8% VALU /
// 59% occ / MfmaUtil 0 => latency-bound, and k_dinv/k_acc ran at
// 391 blocks x 256 thr = ~19% occupancy. Fix: 1024-thread blocks on all
// latency-bound passes (4x resident waves, 1/4 serial chain length),
// 2 nodes/wave in the xw GEMV (4 outstanding dwordx4/lane, interleaved
// shuffle chains). Workspace layout byte-identical to R5.

constexpr int N_NODES = 100000;
constexpr int N_EDGES = 3200000;
constexpr int IN_CH   = 512;
constexpr int HID     = 16;
constexpr int OUT_CH  = 2;

constexpr int NBUCK      = (N_NODES + 255) / 256;   // 391 buckets x 256 nodes
constexpr int BIN_BLOCKS = 320;
constexpr int EPB        = N_EDGES / BIN_BLOCKS;    // 10000 (exact)
constexpr int XW_BLOCKS  = N_NODES / 32;            // 3125 (32 nodes/block, 1024 thr)

typedef __attribute__((ext_vector_type(4))) float floatx4;

// ---- workspace layout (bytes) ----
// 0        hist     int[320][391]  (500480)  per-block bucket counts -> offsets
// 500480   coltot   int[391]
// 502048   bbase    int[392]
// 503616   Wc       float[1024]
// 507712   bconst   float[2] (pad 16)
// 507728   dinv     float[N_NODES]   (400000)
// 907728   t2       float2[N_NODES]  (800000)
// 1707728  binned   int[N_EDGES]     (12.8 MB)  value = (local_tgt<<20)|src

__global__ __launch_bounds__(1024) void k_count_wc(const int* __restrict__ tgt,
                                                   int* __restrict__ hist,
                                                   const float* __restrict__ W1,
                                                   const float* __restrict__ b1,
                                                   const float* __restrict__ W2,
                                                   const float* __restrict__ b2,
                                                   float* __restrict__ Wc,
                                                   float* __restrict__ bconst) {
    if (blockIdx.x == BIN_BLOCKS) {  // weight-fold block
        for (int i = threadIdx.x; i < IN_CH * OUT_CH; i += 1024) {
            int c = i >> 1, o = i & 1;
            float s = 0.f;
#pragma unroll
            for (int h = 0; h < HID; ++h) s += W1[c * HID + h] * W2[h * OUT_CH + o];
            Wc[i] = s;
        }
        if (threadIdx.x < OUT_CH) {
            float bo = b2[threadIdx.x];
#pragma unroll
            for (int h = 0; h < HID; ++h) bo += b1[h] * W2[h * OUT_CH + threadIdx.x];
            bconst[threadIdx.x] = bo;
        }
        return;
    }
    __shared__ int h[NBUCK];
    for (int i = threadIdx.x; i < NBUCK; i += 1024) h[i] = 0;
    __syncthreads();
    int e0 = blockIdx.x * EPB;
    for (int e = e0 + threadIdx.x; e < e0 + EPB; e += 1024)
        atomicAdd(&h[tgt[e] >> 8], 1);
    __syncthreads();
    for (int i = threadIdx.x; i < NBUCK; i += 1024)
        hist[blockIdx.x * NBUCK + i] = h[i];  // dense row, single-writer line
}

// Per bucket b: exclusive scan down the 320-block column; in-place offsets.
__global__ __launch_bounds__(64) void k_colscan(int* __restrict__ hist,
                                                int* __restrict__ coltot) {
    int b = blockIdx.x;
    int lane = threadIdx.x;          // covers blocks 5*lane .. 5*lane+4
    int v[5];
    int s = 0;
#pragma unroll
    for (int j = 0; j < 5; ++j) {
        v[j] = hist[(lane * 5 + j) * NBUCK + b];
        s += v[j];
    }
    int inc = s;
#pragma unroll
    for (int off = 1; off < 64; off <<= 1) {
        int n = __shfl_up(inc, off);
        if (lane >= off) inc += n;
    }
    int excl = inc - s;
#pragma unroll
    for (int j = 0; j < 5; ++j) {
        hist[(lane * 5 + j) * NBUCK + b] = excl;
        excl += v[j];
    }
    if (lane == 63) coltot[b] = inc;
}

__global__ __launch_bounds__(512) void k_basescan(const int* __restrict__ coltot,
                                                  int* __restrict__ bbase) {
    __shared__ int tmp[512];
    int tid = threadIdx.x;
    int v = (tid < NBUCK) ? coltot[tid] : 0;
    tmp[tid] = v;
    __syncthreads();
#pragma unroll
    for (int off = 1; off < 512; off <<= 1) {
        int tv = (tid >= off) ? tmp[tid - off] : 0;
        __syncthreads();
        tmp[tid] += tv;
        __syncthreads();
    }
    if (tid < NBUCK) bbase[tid] = tmp[tid] - v;
    if (tid == NBUCK - 1) bbase[NBUCK] = tmp[tid];  // = N_EDGES
}

// Blocks [0,320): single-pass bin placement with precomputed cursors
//                 (1024 threads => ~10 serial edges/thread instead of 39).
// Blocks [320,3445): t_raw = x@Wc, 2 nodes per wave (4 outstanding
//                 dwordx4/lane), 32 nodes per 1024-thread block.
__global__ __launch_bounds__(1024) void k_bin_xw(const int* __restrict__ ei,
                                                 int* __restrict__ hist,
                                                 const int* __restrict__ bbase,
                                                 int* __restrict__ binned,
                                                 const float* __restrict__ x,
                                                 const float* __restrict__ Wc,
                                                 float2* __restrict__ t2) {
    if (blockIdx.x < BIN_BLOCKS) {
        __shared__ int lcur[NBUCK];
        int blk = blockIdx.x;
        for (int i = threadIdx.x; i < NBUCK; i += 1024)
            lcur[i] = bbase[i] + hist[blk * NBUCK + i];
        __syncthreads();
        int e0 = blk * EPB;
        for (int e = e0 + threadIdx.x; e < e0 + EPB; e += 1024) {
            int tg = ei[N_EDGES + e];
            int b = tg >> 8;
            int pos = atomicAdd(&lcur[b], 1);
            binned[pos] = ((tg & 255) << 20) | ei[e];  // src < 2^20
        }
        return;
    }
    int nb = blockIdx.x - BIN_BLOCKS;
    int wv = threadIdx.x >> 6;
    int lane = threadIdx.x & 63;
    int node = nb * 32 + wv * 2;                 // this wave's 2 nodes
    const floatx4* xr0 = reinterpret_cast<const floatx4*>(
        x + (size_t)node * IN_CH + lane * 8);
    const floatx4* xr1 = reinterpret_cast<const floatx4*>(
        x + (size_t)(node + 1) * IN_CH + lane * 8);
    const floatx4* wr = reinterpret_cast<const floatx4*>(Wc + lane * 16);
    floatx4 a0 = xr0[0], a1 = xr0[1];            // 4 x-loads issued back-to-back
    floatx4 c0 = xr1[0], c1 = xr1[1];
    floatx4 w0 = wr[0], w1 = wr[1], w2 = wr[2], w3 = wr[3];
    float s0 = a0[0]*w0[0] + a0[1]*w0[2] + a0[2]*w1[0] + a0[3]*w1[2]
             + a1[0]*w2[0] + a1[1]*w2[2] + a1[2]*w3[0] + a1[3]*w3[2];
    float s1 = a0[0]*w0[1] + a0[1]*w0[3] + a0[2]*w1[1] + a0[3]*w1[3]
             + a1[0]*w2[1] + a1[1]*w2[3] + a1[2]*w3[1] + a1[3]*w3[3];
    float u0 = c0[0]*w0[0] + c0[1]*w0[2] + c0[2]*w1[0] + c0[3]*w1[2]
             + c1[0]*w2[0] + c1[1]*w2[2] + c1[2]*w3[0] + c1[3]*w3[2];
    float u1 = c0[0]*w0[1] + c0[1]*w0[3] + c0[2]*w1[1] + c0[3]*w1[3]
             + c1[0]*w2[1] + c1[1]*w2[3] + c1[2]*w3[1] + c1[3]*w3[3];
#pragma unroll
    for (int off = 32; off; off >>= 1) {         // 4 chains interleaved (ILP)
        s0 += __shfl_xor(s0, off);
        s1 += __shfl_xor(s1, off);
        u0 += __shfl_xor(u0, off);
        u1 += __shfl_xor(u1, off);
    }
    if (lane == 0) t2[node] = make_float2(s0, s1);          // RAW (no dinv yet)
    else if (lane == 1) t2[node + 1] = make_float2(u0, u1);
}

// Per bucket: local degree count -> dinv; scale t2 in place. 16 waves/block.
__global__ __launch_bounds__(1024) void k_dinv(const int* __restrict__ bbase,
                                               const int* __restrict__ binned,
                                               float* __restrict__ dinv,
                                               float2* __restrict__ t2) {
    __shared__ int cnt[256];
    if (threadIdx.x < 256) cnt[threadIdx.x] = 0;
    __syncthreads();
    int b = blockIdx.x;
    int s = bbase[b], e = bbase[b + 1];
    for (int i = s + threadIdx.x; i < e; i += 1024)
        atomicAdd(&cnt[binned[i] >> 20], 1);
    __syncthreads();
    if (threadIdx.x < 256) {
        int node = (b << 8) + threadIdx.x;
        if (node < N_NODES) {
            float di = rsqrtf((float)(cnt[threadIdx.x] + 1));  // +1 self loop
            dinv[node] = di;
            float2 v = t2[node];
            t2[node] = make_float2(v.x * di, v.y * di);
        }
    }
}

// Per bucket: accumulate pre-scaled t[src] in LDS, fused epilogue, dense out.
// 16 waves/block: ~8 serial edges/thread instead of 32.
__global__ __launch_bounds__(1024) void k_acc(const int* __restrict__ bbase,
                                              const int* __restrict__ binned,
                                              const float2* __restrict__ t2,
                                              const float* __restrict__ dinv,
                                              const float* __restrict__ bconst,
                                              float2* __restrict__ out) {
    __shared__ float acc0[256];
    __shared__ float acc1[256];
    if (threadIdx.x < 256) {
        acc0[threadIdx.x] = 0.f;
        acc1[threadIdx.x] = 0.f;
    }
    __syncthreads();
    int b = blockIdx.x;
    int s = bbase[b], e = bbase[b + 1];
    for (int i = s + threadIdx.x; i < e; i += 1024) {
        int v = binned[i];
        float2 ts = t2[v & 0xFFFFF];    // L2-resident 800 KB table
        atomicAdd(&acc0[v >> 20], ts.x);
        atomicAdd(&acc1[v >> 20], ts.y);
    }
    __syncthreads();
    if (threadIdx.x < 256) {
        int node = (b << 8) + threadIdx.x;
        if (node < N_NODES) {
            float2 self = t2[node];     // already dinv-scaled
            float di = dinv[node];
            out[node] = make_float2(di * (acc0[threadIdx.x] + self.x) + bconst[0],
                                    di * (acc1[threadIdx.x] + self.y) + bconst[1]);
        }
    }
}

extern "C" void kernel_launch(void* const* d_in, const int* in_sizes, int n_in,
                              void* d_out, int out_size, void* d_ws, size_t ws_size,
                              hipStream_t stream) {
    const float* x  = (const float*)d_in[0];
    const int*   ei = (const int*)d_in[1];
    const float* W1 = (const float*)d_in[2];
    const float* b1 = (const float*)d_in[3];
    const float* W2 = (const float*)d_in[4];
    const float* b2 = (const float*)d_in[5];

    char* ws = (char*)d_ws;
    int*    hist   = (int*)   (ws + 0);
    int*    coltot = (int*)   (ws + 500480);
    int*    bbase  = (int*)   (ws + 502048);
    float*  Wc     = (float*) (ws + 503616);
    float*  bconst = (float*) (ws + 507712);
    float*  dinv   = (float*) (ws + 507728);
    float2* t2     = (float2*)(ws + 907728);
    int*    binned = (int*)   (ws + 1707728);

    k_count_wc<<<BIN_BLOCKS + 1, 1024, 0, stream>>>(ei + N_EDGES, hist,
                                                    W1, b1, W2, b2, Wc, bconst);
    k_colscan <<<NBUCK, 64, 0, stream>>>(hist, coltot);
    k_basescan<<<1, 512, 0, stream>>>(coltot, bbase);
    k_bin_xw  <<<BIN_BLOCKS + XW_BLOCKS, 1024, 0, stream>>>(ei, hist, bbase,
                                                            binned, x, Wc, t2);
    k_dinv    <<<NBUCK, 1024, 0, stream>>>(bbase, binned, dinv, t2);
    k_acc     <<<NBUCK, 1024, 0, stream>>>(bbase, binned, t2, dinv, bconst,
                                           (float2*)d_out);
}